// Round 6
// baseline (361.994 us; speedup 1.0000x reference)
//
#include <hip/hip_runtime.h>
#include <math.h>

#define TRANS_SCALE 0.1f

typedef float v2f __attribute__((ext_vector_type(2)));

// ---------------------------------------------------------------------------
// Kernel 1: per-batch affine matrix (B=256 threads total; trivial cost).
// ---------------------------------------------------------------------------
__global__ void uaug_theta_kernel(const float* __restrict__ width,
                                  const float* __restrict__ rand_u,
                                  float* __restrict__ theta, int B) {
    int b = blockIdx.x * blockDim.x + threadIdx.x;
    if (b >= B) return;

    float wt[6];
#pragma unroll
    for (int i = 0; i < 6; ++i) {
        float wd = width[i];
        float sp = log1pf(expf(-fabsf(wd))) + fmaxf(wd, 0.0f);  // softplus
        wt[i] = rand_u[b * 6 + i] * sp - sp * 0.5f;
    }

    float G[3][3];
#pragma unroll
    for (int i = 0; i < 3; ++i)
#pragma unroll
        for (int j = 0; j < 3; ++j) G[i][j] = 0.0f;
    G[0][2] = wt[0] * TRANS_SCALE;
    G[1][2] = wt[1] * TRANS_SCALE;
    G[0][1] = -wt[2] + wt[5];
    G[1][0] = wt[2] + wt[5];
    G[0][0] = wt[3] + wt[4];
    G[1][1] = wt[3] - wt[4];

    const float scale = 1.0f / 64.0f;
    float A[3][3];
#pragma unroll
    for (int i = 0; i < 3; ++i)
#pragma unroll
        for (int j = 0; j < 3; ++j) A[i][j] = G[i][j] * scale;

    float term[3][3], out[3][3];
#pragma unroll
    for (int i = 0; i < 3; ++i)
#pragma unroll
        for (int j = 0; j < 3; ++j) {
            float v = (i == j) ? 1.0f : 0.0f;
            term[i][j] = v;
            out[i][j] = v;
        }
#pragma unroll
    for (int k = 1; k <= 10; ++k) {
        float t2[3][3];
        float inv = 1.0f / (float)k;
#pragma unroll
        for (int i = 0; i < 3; ++i)
#pragma unroll
            for (int j = 0; j < 3; ++j) {
                float s = 0.0f;
#pragma unroll
                for (int l = 0; l < 3; ++l) s += term[i][l] * A[l][j];
                t2[i][j] = s * inv;
            }
#pragma unroll
        for (int i = 0; i < 3; ++i)
#pragma unroll
            for (int j = 0; j < 3; ++j) {
                term[i][j] = t2[i][j];
                out[i][j] += t2[i][j];
            }
    }
#pragma unroll
    for (int s = 0; s < 6; ++s) {
        float t2[3][3];
#pragma unroll
        for (int i = 0; i < 3; ++i)
#pragma unroll
            for (int j = 0; j < 3; ++j) {
                float acc = 0.0f;
#pragma unroll
                for (int l = 0; l < 3; ++l) acc += out[i][l] * out[l][j];
                t2[i][j] = acc;
            }
#pragma unroll
        for (int i = 0; i < 3; ++i)
#pragma unroll
            for (int j = 0; j < 3; ++j) out[i][j] = t2[i][j];
    }

    theta[b * 6 + 0] = out[0][0];
    theta[b * 6 + 1] = out[0][1];
    theta[b * 6 + 2] = out[0][2];
    theta[b * 6 + 3] = out[1][0];
    theta[b * 6 + 4] = out[1][1];
    theta[b * 6 + 5] = out[1][2];
}

// ---------------------------------------------------------------------------
// Kernel 2: affine grid + bilinear grid_sample, fp32, zeros padding,
// align_corners=True.
//
// 2 pixels (an x-pair) per thread. All 24 gather loads are issued into
// register arrays BEFORE any consumption — the R4 profile showed VGPR=16
// with waves stalled ~95% of their life on serialized vmcnt chains; this
// restructure trades registers for memory-level parallelism.
//
// Geometry: 512 px per block -> 98 blocks per image (block-uniform b).
// Grid = 25088 = 8 XCDs x 3136; contiguous chunk per XCD preserves the
// row-reuse L2 locality that cut FETCH_SIZE 397->64 MB in R4.
// ---------------------------------------------------------------------------
#define IMG_W 224
#define IMG_H 224
#define IMG_HW (IMG_W * IMG_H)      /* 50176 */
#define PX_PER_BLOCK 512
#define BLOCKS_PER_IMG (IMG_HW / PX_PER_BLOCK)   /* 98 */

__global__ __launch_bounds__(256) void uaug_sample_kernel(
    const float* __restrict__ img, const float* __restrict__ theta,
    float* __restrict__ out) {
    // XCD-contiguous block swizzle (grid divisible by 8)
    int bid = blockIdx.x;
    int chunk = gridDim.x >> 3;                  // 3136
    int swz = (bid & 7) * chunk + (bid >> 3);

    int b = swz / BLOCKS_PER_IMG;                // block-uniform image index
    int rem = swz - b * BLOCKS_PER_IMG;
    int pix0 = rem * PX_PER_BLOCK + (int)threadIdx.x * 2;  // even
    int hc = pix0 / IMG_W;
    int wc = pix0 - hc * IMG_W;                  // even; pair stays in-row

    // uniform theta (scalar loads)
    const float* th = theta + b * 6;
    float t0 = th[0], t1 = th[1], t2 = th[2];
    float t3 = th[3], t4 = th[4], t5 = th[5];

    const float inv = 2.0f / (float)(IMG_W - 1);
    float ys = (float)hc * inv - 1.0f;
    float ty1 = t1 * ys + t2;                    // gx = t0*xs + ty1
    float ty4 = t4 * ys + t5;                    // gy = t3*xs + ty4

    int   off[2][4];
    float wgt[2][4];
#pragma unroll
    for (int p = 0; p < 2; ++p) {
        float xs = (float)(wc + p) * inv - 1.0f;
        float gx = t0 * xs + ty1;
        float gy = t3 * xs + ty4;

        float ix = (gx + 1.0f) * 0.5f * (float)(IMG_W - 1);
        float iy = (gy + 1.0f) * 0.5f * (float)(IMG_H - 1);

        float ix0f = floorf(ix);
        float iy0f = floorf(iy);
        float wx1 = ix - ix0f;
        float wy1 = iy - iy0f;
        float wx0 = 1.0f - wx1;
        float wy0 = 1.0f - wy1;

        int ix0 = (int)ix0f, iy0 = (int)iy0f;
        int ix1 = ix0 + 1,   iy1 = iy0 + 1;

        bool vx0 = (ix0 >= 0) && (ix0 < IMG_W);
        bool vx1 = (ix1 >= 0) && (ix1 < IMG_W);
        bool vy0 = (iy0 >= 0) && (iy0 < IMG_H);
        bool vy1 = (iy1 >= 0) && (iy1 < IMG_H);

        int cx0 = min(max(ix0, 0), IMG_W - 1);
        int cx1 = min(max(ix1, 0), IMG_W - 1);
        int cy0 = min(max(iy0, 0), IMG_H - 1);
        int cy1 = min(max(iy1, 0), IMG_H - 1);

        wgt[p][0] = wy0 * wx0 * ((vy0 && vx0) ? 1.0f : 0.0f);
        wgt[p][1] = wy0 * wx1 * ((vy0 && vx1) ? 1.0f : 0.0f);
        wgt[p][2] = wy1 * wx0 * ((vy1 && vx0) ? 1.0f : 0.0f);
        wgt[p][3] = wy1 * wx1 * ((vy1 && vx1) ? 1.0f : 0.0f);

        off[p][0] = cy0 * IMG_W + cx0;
        off[p][1] = cy0 * IMG_W + cx1;
        off[p][2] = cy1 * IMG_W + cx0;
        off[p][3] = cy1 * IMG_W + cx1;
    }

    const float* basec = img + (size_t)b * (3 * IMG_HW);

    // ---- issue ALL 24 gathers before any use (MLP) ----
    float v[3][2][4];
#pragma unroll
    for (int c = 0; c < 3; ++c)
#pragma unroll
        for (int p = 0; p < 2; ++p)
#pragma unroll
            for (int k = 0; k < 4; ++k)
                v[c][p][k] = basec[c * IMG_HW + off[p][k]];

    // ---- consume ----
    float* ob = out + (size_t)b * (3 * IMG_HW) + pix0;
#pragma unroll
    for (int c = 0; c < 3; ++c) {
        v2f r;
        r.x = v[c][0][0] * wgt[0][0] + v[c][0][1] * wgt[0][1] +
              v[c][0][2] * wgt[0][2] + v[c][0][3] * wgt[0][3];
        r.y = v[c][1][0] * wgt[1][0] + v[c][1][1] * wgt[1][1] +
              v[c][1][2] * wgt[1][2] + v[c][1][3] * wgt[1][3];
        __builtin_nontemporal_store(r, (v2f*)(ob + c * IMG_HW));
    }
}

extern "C" void kernel_launch(void* const* d_in, const int* in_sizes, int n_in,
                              void* d_out, int out_size, void* d_ws, size_t ws_size,
                              hipStream_t stream) {
    const float* x      = (const float*)d_in[0];
    const float* width  = (const float*)d_in[1];
    const float* rand_u = (const float*)d_in[2];
    float* out = (float*)d_out;

    int B = in_sizes[2] / 6;            // 256

    float* theta = (float*)d_ws;        // B*6 floats

    uaug_theta_kernel<<<(B + 255) / 256, 256, 0, stream>>>(width, rand_u, theta, B);

    int total = B * IMG_HW;             // 12,845,056 pixels
    uaug_sample_kernel<<<total / PX_PER_BLOCK, 256, 0, stream>>>(x, theta, out);
}

// Round 7
// 326.050 us; speedup vs baseline: 1.1102x; 1.1102x over previous
//
#include <hip/hip_runtime.h>
#include <math.h>

#define TRANS_SCALE 0.1f

typedef float v2f  __attribute__((ext_vector_type(2)));              // 8B-aligned
typedef float v2fu __attribute__((ext_vector_type(2), aligned(4)));  // 4B-aligned load

// ---------------------------------------------------------------------------
// Kernel 1: per-batch affine matrix (B=256 threads total; trivial cost).
// ---------------------------------------------------------------------------
__global__ void uaug_theta_kernel(const float* __restrict__ width,
                                  const float* __restrict__ rand_u,
                                  float* __restrict__ theta, int B) {
    int b = blockIdx.x * blockDim.x + threadIdx.x;
    if (b >= B) return;

    float wt[6];
#pragma unroll
    for (int i = 0; i < 6; ++i) {
        float wd = width[i];
        float sp = log1pf(expf(-fabsf(wd))) + fmaxf(wd, 0.0f);  // softplus
        wt[i] = rand_u[b * 6 + i] * sp - sp * 0.5f;
    }

    float G[3][3];
#pragma unroll
    for (int i = 0; i < 3; ++i)
#pragma unroll
        for (int j = 0; j < 3; ++j) G[i][j] = 0.0f;
    G[0][2] = wt[0] * TRANS_SCALE;
    G[1][2] = wt[1] * TRANS_SCALE;
    G[0][1] = -wt[2] + wt[5];
    G[1][0] = wt[2] + wt[5];
    G[0][0] = wt[3] + wt[4];
    G[1][1] = wt[3] - wt[4];

    const float scale = 1.0f / 64.0f;
    float A[3][3];
#pragma unroll
    for (int i = 0; i < 3; ++i)
#pragma unroll
        for (int j = 0; j < 3; ++j) A[i][j] = G[i][j] * scale;

    float term[3][3], out[3][3];
#pragma unroll
    for (int i = 0; i < 3; ++i)
#pragma unroll
        for (int j = 0; j < 3; ++j) {
            float v = (i == j) ? 1.0f : 0.0f;
            term[i][j] = v;
            out[i][j] = v;
        }
#pragma unroll
    for (int k = 1; k <= 10; ++k) {
        float t2[3][3];
        float inv = 1.0f / (float)k;
#pragma unroll
        for (int i = 0; i < 3; ++i)
#pragma unroll
            for (int j = 0; j < 3; ++j) {
                float s = 0.0f;
#pragma unroll
                for (int l = 0; l < 3; ++l) s += term[i][l] * A[l][j];
                t2[i][j] = s * inv;
            }
#pragma unroll
        for (int i = 0; i < 3; ++i)
#pragma unroll
            for (int j = 0; j < 3; ++j) {
                term[i][j] = t2[i][j];
                out[i][j] += t2[i][j];
            }
    }
#pragma unroll
    for (int s = 0; s < 6; ++s) {
        float t2[3][3];
#pragma unroll
        for (int i = 0; i < 3; ++i)
#pragma unroll
            for (int j = 0; j < 3; ++j) {
                float acc = 0.0f;
#pragma unroll
                for (int l = 0; l < 3; ++l) acc += out[i][l] * out[l][j];
                t2[i][j] = acc;
            }
#pragma unroll
        for (int i = 0; i < 3; ++i)
#pragma unroll
            for (int j = 0; j < 3; ++j) out[i][j] = t2[i][j];
    }

    theta[b * 6 + 0] = out[0][0];
    theta[b * 6 + 1] = out[0][1];
    theta[b * 6 + 2] = out[0][2];
    theta[b * 6 + 3] = out[1][0];
    theta[b * 6 + 4] = out[1][1];
    theta[b * 6 + 5] = out[1][2];
}

// ---------------------------------------------------------------------------
// Kernel 2: affine grid + bilinear grid_sample (zeros pad, align_corners).
//
// Bottleneck (R1/R4/R6 evidence): scattered-gather lane-address throughput
// (~1.5 addr/cy/CU). Fix: fetch both x-corners of each sample with ONE
// dwordx2 gather from m=clamp(ix0,0,W-2); select x0/x1 via d=cx-m in {0,1}.
// 6 gather instrs per pixel instead of 12. 2 px/thread, all 12 gathers
// issued before consumption; float2 nontemporal stores.
// ---------------------------------------------------------------------------
#define IMG_W 224
#define IMG_H 224
#define IMG_HW (IMG_W * IMG_H)      /* 50176 */
#define PX_PER_BLOCK 512
#define BLOCKS_PER_IMG (IMG_HW / PX_PER_BLOCK)   /* 98 */

__global__ __launch_bounds__(256) void uaug_sample_kernel(
    const float* __restrict__ img, const float* __restrict__ theta,
    float* __restrict__ out) {
    // XCD-contiguous block swizzle (grid = 25088, divisible by 8)
    int bid = blockIdx.x;
    int chunk = gridDim.x >> 3;                  // 3136
    int swz = (bid & 7) * chunk + (bid >> 3);

    int b = swz / BLOCKS_PER_IMG;                // block-uniform image index
    int rem = swz - b * BLOCKS_PER_IMG;
    int pix0 = rem * PX_PER_BLOCK + (int)threadIdx.x * 2;  // even
    int hc = pix0 / IMG_W;
    int wc = pix0 - hc * IMG_W;                  // even; pair stays in-row

    const float* th = theta + b * 6;
    float t0 = th[0], t1 = th[1], t2 = th[2];
    float t3 = th[3], t4 = th[4], t5 = th[5];

    const float inv = 2.0f / (float)(IMG_W - 1);
    float ys = (float)hc * inv - 1.0f;
    float ty1 = t1 * ys + t2;                    // gx = t0*xs + ty1
    float ty4 = t4 * ys + t5;                    // gy = t3*xs + ty4

    int   row[2][2];    // [pixel][y-corner] clamped rows
    int   mcol[2];      // [pixel] x-segment start (clamped to [0, W-2])
    int   dsel[2][2];   // [pixel][x-corner] offset within segment, 0 or 1
    float wgt[2][4];    // [pixel][corner] weights (validity-masked)
#pragma unroll
    for (int p = 0; p < 2; ++p) {
        float xs = (float)(wc + p) * inv - 1.0f;
        float gx = t0 * xs + ty1;
        float gy = t3 * xs + ty4;

        float ix = (gx + 1.0f) * 0.5f * (float)(IMG_W - 1);
        float iy = (gy + 1.0f) * 0.5f * (float)(IMG_H - 1);

        float ix0f = floorf(ix);
        float iy0f = floorf(iy);
        float wx1 = ix - ix0f;
        float wy1 = iy - iy0f;
        float wx0 = 1.0f - wx1;
        float wy0 = 1.0f - wy1;

        int ix0 = (int)ix0f, iy0 = (int)iy0f;
        int ix1 = ix0 + 1,   iy1 = iy0 + 1;

        bool vx0 = (ix0 >= 0) && (ix0 < IMG_W);
        bool vx1 = (ix1 >= 0) && (ix1 < IMG_W);
        bool vy0 = (iy0 >= 0) && (iy0 < IMG_H);
        bool vy1 = (iy1 >= 0) && (iy1 < IMG_H);

        int cx0 = min(max(ix0, 0), IMG_W - 1);
        int cx1 = min(max(ix1, 0), IMG_W - 1);
        int cy0 = min(max(iy0, 0), IMG_H - 1);
        int cy1 = min(max(iy1, 0), IMG_H - 1);

        int m = min(max(ix0, 0), IMG_W - 2);
        mcol[p] = m;
        dsel[p][0] = cx0 - m;                    // 0 or 1
        dsel[p][1] = cx1 - m;                    // 0 or 1
        row[p][0] = cy0;
        row[p][1] = cy1;

        wgt[p][0] = wy0 * wx0 * ((vy0 && vx0) ? 1.0f : 0.0f);
        wgt[p][1] = wy0 * wx1 * ((vy0 && vx1) ? 1.0f : 0.0f);
        wgt[p][2] = wy1 * wx0 * ((vy1 && vx0) ? 1.0f : 0.0f);
        wgt[p][3] = wy1 * wx1 * ((vy1 && vx1) ? 1.0f : 0.0f);
    }

    const float* basec = img + (size_t)b * (3 * IMG_HW);

    // ---- issue ALL 12 dwordx2 gathers before any use ----
    v2f q[3][2][2];   // [channel][pixel][y-corner] -> 2 adjacent x values
#pragma unroll
    for (int c = 0; c < 3; ++c)
#pragma unroll
        for (int p = 0; p < 2; ++p)
#pragma unroll
            for (int r = 0; r < 2; ++r)
                q[c][p][r] = *(const v2fu*)(basec + c * IMG_HW +
                                            row[p][r] * IMG_W + mcol[p]);

    // ---- consume ----
    float* ob = out + (size_t)b * (3 * IMG_HW) + pix0;
#pragma unroll
    for (int c = 0; c < 3; ++c) {
        float rr[2];
#pragma unroll
        for (int p = 0; p < 2; ++p) {
            float v00 = dsel[p][0] ? q[c][p][0].y : q[c][p][0].x;
            float v01 = dsel[p][1] ? q[c][p][0].y : q[c][p][0].x;
            float v10 = dsel[p][0] ? q[c][p][1].y : q[c][p][1].x;
            float v11 = dsel[p][1] ? q[c][p][1].y : q[c][p][1].x;
            rr[p] = v00 * wgt[p][0] + v01 * wgt[p][1] +
                    v10 * wgt[p][2] + v11 * wgt[p][3];
        }
        v2f r;
        r.x = rr[0];
        r.y = rr[1];
        __builtin_nontemporal_store(r, (v2f*)(ob + c * IMG_HW));
    }
}

extern "C" void kernel_launch(void* const* d_in, const int* in_sizes, int n_in,
                              void* d_out, int out_size, void* d_ws, size_t ws_size,
                              hipStream_t stream) {
    const float* x      = (const float*)d_in[0];
    const float* width  = (const float*)d_in[1];
    const float* rand_u = (const float*)d_in[2];
    float* out = (float*)d_out;

    int B = in_sizes[2] / 6;            // 256

    float* theta = (float*)d_ws;        // B*6 floats

    uaug_theta_kernel<<<(B + 255) / 256, 256, 0, stream>>>(width, rand_u, theta, B);

    int total = B * IMG_HW;             // 12,845,056 pixels
    uaug_sample_kernel<<<total / PX_PER_BLOCK, 256, 0, stream>>>(x, theta, out);
}